// Round 1
// baseline (1317.089 us; speedup 1.0000x reference)
//
#include <hip/hip_runtime.h>
#include <math.h>

// Problem constants (AttentionWriter): B=8,S=1024,M=2048,D=512,H=512,NH=8,Dh=64
#define BB 8
#define SS 1024
#define MM 2048
#define DD 512
#define HH 512
#define NHEAD 8
#define DHEAD 64

// ---------------------------------------------------------------------------
// GEMM: C[rows,N] = act(A[rows,K] @ W[K,N] + bias[N]) * rowscale[row/rsdiv]
// 128x128 tile, K-step 8, 256 threads, 8x8 micro-tile. rows%128==0, N%128==0,
// K%8==0 assumed (true for all launches here).
// ---------------------------------------------------------------------------
__global__ __launch_bounds__(256) void gemm128(
    const float* __restrict__ A, const float* __restrict__ W,
    const float* __restrict__ bias, float* __restrict__ C,
    int K, int N, int act, const float* __restrict__ rowscale, int rsdiv)
{
    __shared__ float As[8][132];   // As[kk][row], pad to 132 (16B-aligned rows)
    __shared__ float Bs[8][128];   // Bs[kk][col]
    const int tid  = threadIdx.x;
    const int row0 = blockIdx.y * 128, col0 = blockIdx.x * 128;
    const int ty = tid >> 4, tx = tid & 15;

    const int arow = tid >> 1,  ak4  = (tid & 1) * 4;
    const int bk   = tid >> 5,  bcol = (tid & 31) * 4;

    const float* Ap = A + (size_t)(row0 + arow) * K + ak4;
    const float* Wp = W + (size_t)bk * N + col0 + bcol;

    float4 aReg = *(const float4*)Ap;
    float4 bReg = *(const float4*)Wp;

    float acc[8][8];
#pragma unroll
    for (int i = 0; i < 8; ++i)
#pragma unroll
        for (int j = 0; j < 8; ++j) acc[i][j] = 0.f;

    for (int k0 = 0; k0 < K; k0 += 8) {
        __syncthreads();
        As[ak4 + 0][arow] = aReg.x;
        As[ak4 + 1][arow] = aReg.y;
        As[ak4 + 2][arow] = aReg.z;
        As[ak4 + 3][arow] = aReg.w;
        *(float4*)&Bs[bk][bcol] = bReg;
        __syncthreads();
        if (k0 + 8 < K) {
            aReg = *(const float4*)(Ap + k0 + 8);
            bReg = *(const float4*)(Wp + (size_t)(k0 + 8) * N);
        }
#pragma unroll
        for (int kk = 0; kk < 8; ++kk) {
            float a[8], b[8];
            *(float4*)&a[0] = *(const float4*)&As[kk][ty * 8];
            *(float4*)&a[4] = *(const float4*)&As[kk][ty * 8 + 4];
            // col fragment split: cols {4tx..4tx+3} and {64+4tx..64+4tx+3}
            *(float4*)&b[0] = *(const float4*)&Bs[kk][tx * 4];
            *(float4*)&b[4] = *(const float4*)&Bs[kk][64 + tx * 4];
#pragma unroll
            for (int i = 0; i < 8; ++i)
#pragma unroll
                for (int j = 0; j < 8; ++j)
                    acc[i][j] = fmaf(a[i], b[j], acc[i][j]);
        }
    }

#pragma unroll
    for (int i = 0; i < 8; ++i) {
        const int r = row0 + ty * 8 + i;
        const float sc = rowscale ? rowscale[r / rsdiv] : 1.0f;
#pragma unroll
        for (int half = 0; half < 2; ++half) {
            const int c = col0 + half * 64 + tx * 4;
            float4 v;
            v.x = acc[i][half * 4 + 0] + bias[c + 0];
            v.y = acc[i][half * 4 + 1] + bias[c + 1];
            v.z = acc[i][half * 4 + 2] + bias[c + 2];
            v.w = acc[i][half * 4 + 3] + bias[c + 3];
            if (act == 1) {
                v.x = fmaxf(v.x, 0.f); v.y = fmaxf(v.y, 0.f);
                v.z = fmaxf(v.z, 0.f); v.w = fmaxf(v.w, 0.f);
            }
            v.x *= sc; v.y *= sc; v.z *= sc; v.w *= sc;
            *(float4*)&C[(size_t)r * N + c] = v;
        }
    }
}

// ---------------------------------------------------------------------------
// Flash attention: out[b,m,h*64+d] = softmax(Q K^T / 8) V  per (b, head).
// Tile: 64 q-rows x full d=64; S-chunks of 64. 256 threads, 4x4 micro-tiles.
// LDS: Qt[c][row], KP (K^T then P^T, shared), Vs[j][d]; pad 65 => conflict-free
// scalar reads (broadcast). Writes out into the q buffer (exact same slice the
// block read -> safe aliasing).
// ---------------------------------------------------------------------------
__global__ __launch_bounds__(256) void attn_kernel(
    const float* __restrict__ qh, const float* __restrict__ kh,
    const float* __restrict__ vh, float* __restrict__ outp)
{
    __shared__ float Qt[64][65];   // Qt[c][row]
    __shared__ float KP[64][65];   // K phase: KP[c][j]; P phase: KP[j][row]
    __shared__ float Vs[64][65];   // Vs[j][d]
    const int tid = threadIdx.x;
    const int mt = blockIdx.x, h = blockIdx.y, b = blockIdx.z;
    const int ty = tid >> 4, tx = tid & 15;
    const int lr = tid >> 4, lc = (tid & 15) * 4;

#pragma unroll
    for (int r = 0; r < 4; ++r) {
        const int row = lr + r * 16;
        const float4 v = *(const float4*)(qh +
            ((size_t)(b * MM + mt * 64 + row)) * HH + h * DHEAD + lc);
        Qt[lc + 0][row] = v.x; Qt[lc + 1][row] = v.y;
        Qt[lc + 2][row] = v.z; Qt[lc + 3][row] = v.w;
    }

    float out_acc[4][4];
    float mrun[4], lrun[4];
#pragma unroll
    for (int i = 0; i < 4; ++i) {
        mrun[i] = -1e30f; lrun[i] = 0.f;
#pragma unroll
        for (int d = 0; d < 4; ++d) out_acc[i][d] = 0.f;
    }

    for (int s0 = 0; s0 < SS; s0 += 64) {
        __syncthreads();  // prev PV done (and Qt visible on first iter)
#pragma unroll
        for (int r = 0; r < 4; ++r) {
            const int j = lr + r * 16;
            const float4 kv = *(const float4*)(kh +
                ((size_t)(b * SS + s0 + j)) * HH + h * DHEAD + lc);
            KP[lc + 0][j] = kv.x; KP[lc + 1][j] = kv.y;
            KP[lc + 2][j] = kv.z; KP[lc + 3][j] = kv.w;
            const float4 vv = *(const float4*)(vh +
                ((size_t)(b * SS + s0 + j)) * HH + h * DHEAD + lc);
            Vs[j][lc + 0] = vv.x; Vs[j][lc + 1] = vv.y;
            Vs[j][lc + 2] = vv.z; Vs[j][lc + 3] = vv.w;
        }
        __syncthreads();

        float sc[4][4];
#pragma unroll
        for (int i = 0; i < 4; ++i)
#pragma unroll
            for (int j = 0; j < 4; ++j) sc[i][j] = 0.f;
        for (int kk = 0; kk < 64; ++kk) {
            float a[4], bb[4];
#pragma unroll
            for (int i = 0; i < 4; ++i) a[i] = Qt[kk][ty * 4 + i];
#pragma unroll
            for (int j = 0; j < 4; ++j) bb[j] = KP[kk][tx * 4 + j];
#pragma unroll
            for (int i = 0; i < 4; ++i)
#pragma unroll
                for (int j = 0; j < 4; ++j)
                    sc[i][j] = fmaf(a[i], bb[j], sc[i][j]);
        }

        float p[4][4];
#pragma unroll
        for (int i = 0; i < 4; ++i) {
#pragma unroll
            for (int j = 0; j < 4; ++j) sc[i][j] *= 0.125f;  // 1/sqrt(64)
            float mx = fmaxf(fmaxf(sc[i][0], sc[i][1]), fmaxf(sc[i][2], sc[i][3]));
#pragma unroll
            for (int msk = 1; msk < 16; msk <<= 1) mx = fmaxf(mx, __shfl_xor(mx, msk));
            const float nm = fmaxf(mrun[i], mx);
            const float scale = __expf(mrun[i] - nm);
            mrun[i] = nm;
            float ps = 0.f;
#pragma unroll
            for (int j = 0; j < 4; ++j) { p[i][j] = __expf(sc[i][j] - nm); ps += p[i][j]; }
#pragma unroll
            for (int msk = 1; msk < 16; msk <<= 1) ps += __shfl_xor(ps, msk);
            lrun[i] = lrun[i] * scale + ps;
#pragma unroll
            for (int d = 0; d < 4; ++d) out_acc[i][d] *= scale;
        }
        __syncthreads();  // everyone done reading K from KP
#pragma unroll
        for (int i = 0; i < 4; ++i)
#pragma unroll
            for (int j = 0; j < 4; ++j)
                KP[tx * 4 + j][ty * 4 + i] = p[i][j];   // P^T
        __syncthreads();

        for (int kk = 0; kk < 64; ++kk) {
            float a[4], bb[4];
#pragma unroll
            for (int i = 0; i < 4; ++i) a[i] = KP[kk][ty * 4 + i];
#pragma unroll
            for (int d = 0; d < 4; ++d) bb[d] = Vs[kk][tx * 4 + d];
#pragma unroll
            for (int i = 0; i < 4; ++i)
#pragma unroll
                for (int d = 0; d < 4; ++d)
                    out_acc[i][d] = fmaf(a[i], bb[d], out_acc[i][d]);
        }
    }

#pragma unroll
    for (int i = 0; i < 4; ++i) {
        const float inv = 1.0f / lrun[i];
        float4 v;
        v.x = out_acc[i][0] * inv; v.y = out_acc[i][1] * inv;
        v.z = out_acc[i][2] * inv; v.w = out_acc[i][3] * inv;
        *(float4*)&outp[((size_t)(b * MM + mt * 64 + ty * 4 + i)) * HH +
                        h * DHEAD + tx * 4] = v;
    }
}

// imp[row] = sigmoid(dot(h1[row,0:256], Wi2) + bi2); one wave per row
__global__ __launch_bounds__(256) void imp_kernel(
    const float* __restrict__ h1, const float* __restrict__ Wi2,
    const float* __restrict__ bi2, float* __restrict__ imp)
{
    const int wv = threadIdx.x >> 6, lane = threadIdx.x & 63;
    const int row = blockIdx.x * 4 + wv;
    const float4 hv = *(const float4*)(h1 + (size_t)row * 256 + lane * 4);
    const float4 wvv = *(const float4*)(Wi2 + lane * 4);
    float s = hv.x * wvv.x + hv.y * wvv.y + hv.z * wvv.z + hv.w * wvv.w;
#pragma unroll
    for (int m = 1; m < 64; m <<= 1) s += __shfl_xor(s, m);
    if (lane == 0) imp[row] = 1.0f / (1.0f + expf(-(s + bi2[0])));
}

// per batch: mean(imp), last index with imp>0.5, exists
__global__ __launch_bounds__(256) void impstats_kernel(
    const float* __restrict__ imp, float* __restrict__ imp_mean,
    int* __restrict__ s_star, int* __restrict__ exists)
{
    const int b = blockIdx.x, tid = threadIdx.x;
    float sum = 0.f; int last = -1;
    for (int s = tid; s < SS; s += 256) {
        const float v = imp[b * SS + s];
        sum += v;
        if (v > 0.5f) last = s;
    }
#pragma unroll
    for (int m = 1; m < 64; m <<= 1) {
        sum += __shfl_xor(sum, m);
        last = max(last, __shfl_xor(last, m));
    }
    __shared__ float ssum[4]; __shared__ int slast[4];
    if ((tid & 63) == 0) { ssum[tid >> 6] = sum; slast[tid >> 6] = last; }
    __syncthreads();
    if (tid == 0) {
        const float t = ssum[0] + ssum[1] + ssum[2] + ssum[3];
        const int ml = max(max(slast[0], slast[1]), max(slast[2], slast[3]));
        imp_mean[b] = t / (float)SS;
        exists[b] = (ml >= 0) ? 1 : 0;
        s_star[b] = (ml >= 0) ? ml : (SS - 1);
    }
}

// rowmean over H of write_weights; one wave per row
__global__ __launch_bounds__(256) void rowmean_kernel(
    const float* __restrict__ ww, float* __restrict__ rm)
{
    const int wv = threadIdx.x >> 6, lane = threadIdx.x & 63;
    const int row = blockIdx.x * 4 + wv;
    const float* p = ww + (size_t)row * HH + lane * 8;
    const float4 v0 = *(const float4*)p;
    const float4 v1 = *(const float4*)(p + 4);
    float s = v0.x + v0.y + v0.z + v0.w + v1.x + v1.y + v1.z + v1.w;
#pragma unroll
    for (int m = 1; m < 64; m <<= 1) s += __shfl_xor(s, m);
    if (lane == 0) rm[row] = s * (1.0f / (float)HH);
}

// per batch: first-occurrence argmax over M rowmeans
__global__ __launch_bounds__(256) void argmax_kernel(
    const float* __restrict__ rm, int* __restrict__ pos)
{
    const int b = blockIdx.x, tid = threadIdx.x;
    float best = -3.0e38f; int bidx = 1 << 30;
    for (int m = tid; m < MM; m += 256) {
        const float v = rm[b * MM + m];
        if (v > best || (v == best && m < bidx)) { best = v; bidx = m; }
    }
#pragma unroll
    for (int msk = 1; msk < 64; msk <<= 1) {
        const float ov = __shfl_xor(best, msk);
        const int oi = __shfl_xor(bidx, msk);
        if (ov > best || (ov == best && oi < bidx)) { best = ov; bidx = oi; }
    }
    __shared__ float sv[4]; __shared__ int si[4];
    if ((tid & 63) == 0) { sv[tid >> 6] = best; si[tid >> 6] = bidx; }
    __syncthreads();
    if (tid == 0) {
        for (int w = 1; w < 4; ++w)
            if (sv[w] > best || (sv[w] == best && si[w] < bidx)) { best = sv[w]; bidx = si[w]; }
        pos[b] = bidx;
    }
}

// per batch: upd = tanh(relu([old,sel]@Wu1+bu1)@Wu2+bu2); write updated row
__global__ __launch_bounds__(256) void update_kernel(
    const float* __restrict__ mb, const float* __restrict__ ni,
    const float* __restrict__ Wu1, const float* __restrict__ bu1,
    const float* __restrict__ Wu2, const float* __restrict__ bu2,
    const float* __restrict__ wwp, const int* __restrict__ pos,
    const int* __restrict__ s_star, const int* __restrict__ exists,
    float* __restrict__ outu)
{
    const int b = blockIdx.x, tid = threadIdx.x;
    __shared__ float comb[2 * DD];
    __shared__ float hu[HH];
    const int p = pos[b], ss = s_star[b], ex = exists[b];
    const float* oldp = mb + ((size_t)(b * MM + p)) * DD;
    const float* selp = ni + ((size_t)(b * SS + ss)) * DD;
    for (int i = tid; i < DD; i += 256) { comb[i] = oldp[i]; comb[DD + i] = selp[i]; }
    __syncthreads();
#pragma unroll
    for (int t = 0; t < 2; ++t) {
        const int n = tid + t * 256;
        float a = bu1[n];
        for (int k = 0; k < 2 * DD; ++k) a = fmaf(comb[k], Wu1[(size_t)k * HH + n], a);
        hu[n] = fmaxf(a, 0.f);
    }
    __syncthreads();
#pragma unroll
    for (int t = 0; t < 2; ++t) {
        const int n = tid + t * 256;
        float a = bu2[n];
        for (int k = 0; k < HH; ++k) a = fmaf(hu[k], Wu2[(size_t)k * HH + n], a);
        const float upd = tanhf(a);
        const float wwv = wwp[((size_t)(b * MM + p)) * HH + n];
        const float ov = oldp[n];
        outu[((size_t)(b * MM + p)) * DD + n] = ex ? fmaf(upd, wwv, ov) : ov;
    }
}

extern "C" void kernel_launch(void* const* d_in, const int* in_sizes, int n_in,
                              void* d_out, int out_size, void* d_ws, size_t ws_size,
                              hipStream_t stream)
{
    const float* new_info    = (const float*)d_in[0];
    const float* memory_bank = (const float*)d_in[1];
    const float* W_in = (const float*)d_in[2];  const float* b_in = (const float*)d_in[3];
    const float* Wq   = (const float*)d_in[4];  const float* bq   = (const float*)d_in[5];
    const float* Wk   = (const float*)d_in[6];  const float* bk   = (const float*)d_in[7];
    const float* Wv   = (const float*)d_in[8];  const float* bv   = (const float*)d_in[9];
    const float* Wo   = (const float*)d_in[10]; const float* bo   = (const float*)d_in[11];
    const float* Wi1  = (const float*)d_in[12]; const float* bi1  = (const float*)d_in[13];
    const float* Wi2  = (const float*)d_in[14]; const float* bi2  = (const float*)d_in[15];
    const float* Wu1  = (const float*)d_in[16]; const float* bu1  = (const float*)d_in[17];
    const float* Wu2  = (const float*)d_in[18]; const float* bu2  = (const float*)d_in[19];

    float* out = (float*)d_out;
    float* out_updated = out;                       // B*M*D = 8,388,608
    float* out_ww      = out + (size_t)BB * MM * HH;        // 8,388,608
    float* out_imp     = out + 2 * (size_t)BB * MM * HH;    // 8192

    // workspace layout (floats); total ~29.4M floats (~118 MB)
    float* ws = (float*)d_ws;
    float* info_proj = ws;                              // B*S*H  = 4,194,304
    float* mem_proj  = info_proj + (size_t)BB * SS * HH; // B*M*H  = 8,388,608
    float* khb       = mem_proj + (size_t)BB * MM * HH;  // B*S*H
    float* vhb       = khb + (size_t)BB * SS * HH;       // B*S*H
    float* qhb       = vhb + (size_t)BB * SS * HH;       // B*M*H  (attn out aliases)
    float* small     = qhb + (size_t)BB * MM * HH;
    float* hidden1   = qhb;                              // B*S*(H/2), reused before qh gemm
    float* rowmean   = small;                            // B*M = 16,384
    float* imp_mean  = rowmean + (size_t)BB * MM;        // 8
    int*   ipos      = (int*)(imp_mean + BB);            // 8
    int*   istar     = ipos + BB;                        // 8
    int*   iexists   = istar + BB;                       // 8

    const dim3 blk(256);

    // updated := memory_bank (row updates applied at the end); decay^0 == 1
    hipMemcpyAsync(out_updated, memory_bank,
                   (size_t)BB * MM * DD * sizeof(float),
                   hipMemcpyDeviceToDevice, stream);

    // projections into hidden space
    gemm128<<<dim3(4, 64), blk, 0, stream>>>(new_info, W_in, b_in, info_proj,
                                             DD, HH, 0, nullptr, 1);
    gemm128<<<dim3(4, 128), blk, 0, stream>>>(memory_bank, W_in, b_in, mem_proj,
                                              DD, HH, 0, nullptr, 1);
    // importance MLP
    gemm128<<<dim3(2, 64), blk, 0, stream>>>(info_proj, Wi1, bi1, hidden1,
                                             HH, HH / 2, 1, nullptr, 1);
    imp_kernel<<<dim3((BB * SS) / 4), blk, 0, stream>>>(hidden1, Wi2, bi2, out_imp);
    impstats_kernel<<<dim3(BB), blk, 0, stream>>>(out_imp, imp_mean, istar, iexists);
    // Q/K/V projections (hidden1 region now free -> qhb)
    gemm128<<<dim3(4, 128), blk, 0, stream>>>(mem_proj, Wq, bq, qhb,
                                              HH, HH, 0, nullptr, 1);
    gemm128<<<dim3(4, 64), blk, 0, stream>>>(info_proj, Wk, bk, khb,
                                             HH, HH, 0, nullptr, 1);
    gemm128<<<dim3(4, 64), blk, 0, stream>>>(info_proj, Wv, bv, vhb,
                                             HH, HH, 0, nullptr, 1);
    // attention (writes back into qhb; each block writes exactly what it read)
    attn_kernel<<<dim3(MM / 64, NHEAD, BB), blk, 0, stream>>>(qhb, khb, vhb, qhb);
    // output projection, scaled by per-batch mean importance -> write_weights
    gemm128<<<dim3(4, 128), blk, 0, stream>>>(qhb, Wo, bo, out_ww,
                                              HH, HH, 0, imp_mean, MM);
    // slot selection + final row update
    rowmean_kernel<<<dim3((BB * MM) / 4), blk, 0, stream>>>(out_ww, rowmean);
    argmax_kernel<<<dim3(BB), blk, 0, stream>>>(rowmean, ipos);
    update_kernel<<<dim3(BB), blk, 0, stream>>>(memory_bank, new_info,
                                                Wu1, bu1, Wu2, bu2, out_ww,
                                                ipos, istar, iexists, out_updated);
}

// Round 2
// 1132.072 us; speedup vs baseline: 1.1634x; 1.1634x over previous
//
#include <hip/hip_runtime.h>
#include <math.h>

// Problem constants (AttentionWriter): B=8,S=1024,M=2048,D=512,H=512,NH=8,Dh=64
#define BB 8
#define SS 1024
#define MM 2048
#define DD 512
#define HH 512
#define NHEAD 8
#define DHEAD 64

// ---------------------------------------------------------------------------
// GEMM: C[rows,N] = act(A[rows,K] @ W[K,N] + bias[N]) * rowscale[row/rsdiv]
// 128x128 tile, K-step 8, 256 threads, 8x8 micro-tile.
// ---------------------------------------------------------------------------
__global__ __launch_bounds__(256) void gemm128(
    const float* __restrict__ A, const float* __restrict__ W,
    const float* __restrict__ bias, float* __restrict__ C,
    int K, int N, int act, const float* __restrict__ rowscale, int rsdiv)
{
    __shared__ float As[8][132];
    __shared__ float Bs[8][128];
    const int tid  = threadIdx.x;
    const int row0 = blockIdx.y * 128, col0 = blockIdx.x * 128;
    const int ty = tid >> 4, tx = tid & 15;

    const int arow = tid >> 1,  ak4  = (tid & 1) * 4;
    const int bk   = tid >> 5,  bcol = (tid & 31) * 4;

    const float* Ap = A + (size_t)(row0 + arow) * K + ak4;
    const float* Wp = W + (size_t)bk * N + col0 + bcol;

    float4 aReg = *(const float4*)Ap;
    float4 bReg = *(const float4*)Wp;

    float acc[8][8];
#pragma unroll
    for (int i = 0; i < 8; ++i)
#pragma unroll
        for (int j = 0; j < 8; ++j) acc[i][j] = 0.f;

    for (int k0 = 0; k0 < K; k0 += 8) {
        __syncthreads();
        As[ak4 + 0][arow] = aReg.x;
        As[ak4 + 1][arow] = aReg.y;
        As[ak4 + 2][arow] = aReg.z;
        As[ak4 + 3][arow] = aReg.w;
        *(float4*)&Bs[bk][bcol] = bReg;
        __syncthreads();
        if (k0 + 8 < K) {
            aReg = *(const float4*)(Ap + k0 + 8);
            bReg = *(const float4*)(Wp + (size_t)(k0 + 8) * N);
        }
#pragma unroll
        for (int kk = 0; kk < 8; ++kk) {
            float a[8], b[8];
            *(float4*)&a[0] = *(const float4*)&As[kk][ty * 8];
            *(float4*)&a[4] = *(const float4*)&As[kk][ty * 8 + 4];
            *(float4*)&b[0] = *(const float4*)&Bs[kk][tx * 4];
            *(float4*)&b[4] = *(const float4*)&Bs[kk][64 + tx * 4];
#pragma unroll
            for (int i = 0; i < 8; ++i)
#pragma unroll
                for (int j = 0; j < 8; ++j)
                    acc[i][j] = fmaf(a[i], b[j], acc[i][j]);
        }
    }

#pragma unroll
    for (int i = 0; i < 8; ++i) {
        const int r = row0 + ty * 8 + i;
        const float sc = rowscale ? rowscale[r / rsdiv] : 1.0f;
#pragma unroll
        for (int half = 0; half < 2; ++half) {
            const int c = col0 + half * 64 + tx * 4;
            float4 v;
            v.x = acc[i][half * 4 + 0] + bias[c + 0];
            v.y = acc[i][half * 4 + 1] + bias[c + 1];
            v.z = acc[i][half * 4 + 2] + bias[c + 2];
            v.w = acc[i][half * 4 + 3] + bias[c + 3];
            if (act == 1) {
                v.x = fmaxf(v.x, 0.f); v.y = fmaxf(v.y, 0.f);
                v.z = fmaxf(v.z, 0.f); v.w = fmaxf(v.w, 0.f);
            }
            v.x *= sc; v.y *= sc; v.z *= sc; v.w *= sc;
            *(float4*)&C[(size_t)r * N + c] = v;
        }
    }
}

// ---------------------------------------------------------------------------
// Flash attention v2: per (b,h): 128 q-rows per block, kv-chunks of 64.
// 256 threads (16 ty x 16 tx), 8q x 4kv micro-tile (QK^T) and 8q x 4d (PV).
// LDS 64KB: Qt[64][128] (Q^T, XOR-swizzled) | Kt[64][64] (K^T, swizzled;
// aliased by P^T halves [32][128]) | Vs[64][64] (linear).
// XOR swizzle: 16B-frag index f_phys = f ^ (row>>2 masked) -> all transpose
// writes and fragment reads are bank-conflict-free per quarter-wave phase.
// ---------------------------------------------------------------------------
#define LDS_KT 8192
#define LDS_VS 12288

#define LOAD_KV(t)                                                              \
    {                                                                           \
        const float* Kc = Kg + (size_t)((t) * 64) * HH;                         \
        const float* Vc = Vg + (size_t)((t) * 64) * HH;                         \
        _Pragma("unroll")                                                       \
        for (int r = 0; r < 4; ++r)                                             \
            kf[r] = *(const float4*)(Kc + (size_t)(ty * 4 + r) * HH + tx * 4);  \
        _Pragma("unroll")                                                       \
        for (int r = 0; r < 4; ++r)                                             \
            vf[r] = *(const float4*)(Vc + (size_t)(ty + 16 * r) * HH + tx * 4); \
    }

#define WRITE_KV()                                                              \
    {                                                                           \
        const int fk = (ty ^ tx) << 2;                                          \
        _Pragma("unroll")                                                       \
        for (int c = 0; c < 4; ++c) {                                           \
            float4 w;                                                           \
            w.x = (&kf[0].x)[c]; w.y = (&kf[1].x)[c];                           \
            w.z = (&kf[2].x)[c]; w.w = (&kf[3].x)[c];                           \
            *(float4*)&lds[LDS_KT + (4 * tx + c) * 64 + fk] = w;                \
        }                                                                       \
        _Pragma("unroll")                                                       \
        for (int r = 0; r < 4; ++r)                                             \
            *(float4*)&lds[LDS_VS + (ty + 16 * r) * 64 + tx * 4] = vf[r];       \
    }

__global__ __launch_bounds__(256) void attn_kernel(
    const float* __restrict__ qh, const float* __restrict__ kh,
    const float* __restrict__ vh, float* __restrict__ outp)
{
    __shared__ float lds[16384];  // 64KB
    const int tid = threadIdx.x;
    const int ty = tid >> 4, tx = tid & 15;
    const int mt = blockIdx.x, h = blockIdx.y, b = blockIdx.z;
    const int m0 = mt * 128;

    const float* Qg = qh + ((size_t)(b * MM + m0)) * HH + h * DHEAD;
    const float* Kg = kh + ((size_t)b * SS) * HH + h * DHEAD;
    const float* Vg = vh + ((size_t)b * SS) * HH + h * DHEAD;

    // ---- stage Q transposed+swizzled: Qt[kk][i], f_phys = (i>>2) ^ (kk>>2)
#pragma unroll
    for (int rr = 0; rr < 2; ++rr) {
        const int task = tid + rr * 256;
        const int qb = task >> 4;        // i-frag 0..31
        const int db = task & 15;        // kk-frag 0..15
        float4 r0 = *(const float4*)(Qg + (size_t)(qb * 4 + 0) * HH + db * 4);
        float4 r1 = *(const float4*)(Qg + (size_t)(qb * 4 + 1) * HH + db * 4);
        float4 r2 = *(const float4*)(Qg + (size_t)(qb * 4 + 2) * HH + db * 4);
        float4 r3 = *(const float4*)(Qg + (size_t)(qb * 4 + 3) * HH + db * 4);
        const int fq = (qb ^ db) << 2;
#pragma unroll
        for (int c = 0; c < 4; ++c) {
            float4 w;
            w.x = (&r0.x)[c]; w.y = (&r1.x)[c]; w.z = (&r2.x)[c]; w.w = (&r3.x)[c];
            *(float4*)&lds[(db * 4 + c) * 128 + fq] = w;
        }
    }

    float4 kf[4], vf[4];
    LOAD_KV(0);
    WRITE_KV();

    float oacc[8][4];
    float mrun[8], lrun[8];
#pragma unroll
    for (int i = 0; i < 8; ++i) {
        mrun[i] = -1e30f; lrun[i] = 0.f;
#pragma unroll
        for (int c = 0; c < 4; ++c) oacc[i][c] = 0.f;
    }

    for (int t = 0; t < SS / 64; ++t) {
        __syncthreads();                 // staged Kt/Vs (and Qt) visible
        if (t < SS / 64 - 1) LOAD_KV(t + 1);

        // ---- QK^T: s[8][4]
        float s[8][4];
#pragma unroll
        for (int i = 0; i < 8; ++i)
#pragma unroll
            for (int j = 0; j < 4; ++j) s[i][j] = 0.f;

        for (int kk4 = 0; kk4 < 16; ++kk4) {
            const int sw = kk4 & 15;
#pragma unroll
            for (int c = 0; c < 4; ++c) {
                const int kk = kk4 * 4 + c;
                const float4 a0 = *(const float4*)&lds[kk * 128 + (((2 * ty) ^ sw) << 2)];
                const float4 a1 = *(const float4*)&lds[kk * 128 + (((2 * ty + 1) ^ sw) << 2)];
                const float4 b0 = *(const float4*)&lds[LDS_KT + kk * 64 + ((tx ^ sw) << 2)];
#define FMA4(si, av)                              \
    si[0] = fmaf(av, b0.x, si[0]);                \
    si[1] = fmaf(av, b0.y, si[1]);                \
    si[2] = fmaf(av, b0.z, si[2]);                \
    si[3] = fmaf(av, b0.w, si[3]);
                FMA4(s[0], a0.x) FMA4(s[1], a0.y) FMA4(s[2], a0.z) FMA4(s[3], a0.w)
                FMA4(s[4], a1.x) FMA4(s[5], a1.y) FMA4(s[6], a1.z) FMA4(s[7], a1.w)
#undef FMA4
            }
        }

        // ---- online softmax (rows replicated across the 16 tx lanes)
#pragma unroll
        for (int i = 0; i < 8; ++i) {
            s[i][0] *= 0.125f; s[i][1] *= 0.125f; s[i][2] *= 0.125f; s[i][3] *= 0.125f;
            float mx = fmaxf(fmaxf(s[i][0], s[i][1]), fmaxf(s[i][2], s[i][3]));
#pragma unroll
            for (int msk = 1; msk < 16; msk <<= 1) mx = fmaxf(mx, __shfl_xor(mx, msk));
            const float nm = fmaxf(mrun[i], mx);
            const float sc = __expf(mrun[i] - nm);
            mrun[i] = nm;
            float p0 = __expf(s[i][0] - nm), p1 = __expf(s[i][1] - nm);
            float p2 = __expf(s[i][2] - nm), p3 = __expf(s[i][3] - nm);
            s[i][0] = p0; s[i][1] = p1; s[i][2] = p2; s[i][3] = p3;
            float ps = p0 + p1 + p2 + p3;
#pragma unroll
            for (int msk = 1; msk < 16; msk <<= 1) ps += __shfl_xor(ps, msk);
            lrun[i] = lrun[i] * sc + ps;
            oacc[i][0] *= sc; oacc[i][1] *= sc; oacc[i][2] *= sc; oacc[i][3] *= sc;
        }

        // ---- PV in two j-halves; P^T[jh][i] aliases Kt, f_phys = f ^ (jh>>2)
#pragma unroll
        for (int half = 0; half < 2; ++half) {
            __syncthreads();             // Kt reads (or prev P^T reads) done
            if ((tx >> 3) == half) {
                const int txl = tx & 7;
#pragma unroll
                for (int jj = 0; jj < 4; ++jj) {
                    const int jh = 4 * txl + jj;
                    const float4 w0 = make_float4(s[0][jj], s[1][jj], s[2][jj], s[3][jj]);
                    const float4 w1 = make_float4(s[4][jj], s[5][jj], s[6][jj], s[7][jj]);
                    *(float4*)&lds[LDS_KT + jh * 128 + (((2 * ty) ^ txl) << 2)] = w0;
                    *(float4*)&lds[LDS_KT + jh * 128 + (((2 * ty + 1) ^ txl) << 2)] = w1;
                }
            }
            __syncthreads();
#pragma unroll 4
            for (int jl = 0; jl < 32; ++jl) {
                const int swp = (jl >> 2) & 7;
                const float4 a0 = *(const float4*)&lds[LDS_KT + jl * 128 + (((2 * ty) ^ swp) << 2)];
                const float4 a1 = *(const float4*)&lds[LDS_KT + jl * 128 + (((2 * ty + 1) ^ swp) << 2)];
                const float4 b0 = *(const float4*)&lds[LDS_VS + (half * 32 + jl) * 64 + tx * 4];
#define FMA4(oi, av)                              \
    oi[0] = fmaf(av, b0.x, oi[0]);                \
    oi[1] = fmaf(av, b0.y, oi[1]);                \
    oi[2] = fmaf(av, b0.z, oi[2]);                \
    oi[3] = fmaf(av, b0.w, oi[3]);
                FMA4(oacc[0], a0.x) FMA4(oacc[1], a0.y) FMA4(oacc[2], a0.z) FMA4(oacc[3], a0.w)
                FMA4(oacc[4], a1.x) FMA4(oacc[5], a1.y) FMA4(oacc[6], a1.z) FMA4(oacc[7], a1.w)
#undef FMA4
            }
        }

        __syncthreads();                 // Vs/P^T reads done before restaging
        if (t < SS / 64 - 1) WRITE_KV();
    }

#pragma unroll
    for (int i = 0; i < 8; ++i) {
        const float inv = 1.0f / lrun[i];
        float4 v;
        v.x = oacc[i][0] * inv; v.y = oacc[i][1] * inv;
        v.z = oacc[i][2] * inv; v.w = oacc[i][3] * inv;
        *(float4*)(outp + ((size_t)(b * MM + m0 + 8 * ty + i)) * HH + h * DHEAD + tx * 4) = v;
    }
}

// imp[row] = sigmoid(dot(h1[row,0:256], Wi2) + bi2); one wave per row
__global__ __launch_bounds__(256) void imp_kernel(
    const float* __restrict__ h1, const float* __restrict__ Wi2,
    const float* __restrict__ bi2, float* __restrict__ imp)
{
    const int wv = threadIdx.x >> 6, lane = threadIdx.x & 63;
    const int row = blockIdx.x * 4 + wv;
    const float4 hv = *(const float4*)(h1 + (size_t)row * 256 + lane * 4);
    const float4 wvv = *(const float4*)(Wi2 + lane * 4);
    float s = hv.x * wvv.x + hv.y * wvv.y + hv.z * wvv.z + hv.w * wvv.w;
#pragma unroll
    for (int m = 1; m < 64; m <<= 1) s += __shfl_xor(s, m);
    if (lane == 0) imp[row] = 1.0f / (1.0f + expf(-(s + bi2[0])));
}

// per batch: mean(imp), last index with imp>0.5, exists
__global__ __launch_bounds__(256) void impstats_kernel(
    const float* __restrict__ imp, float* __restrict__ imp_mean,
    int* __restrict__ s_star, int* __restrict__ exists)
{
    const int b = blockIdx.x, tid = threadIdx.x;
    float sum = 0.f; int last = -1;
    for (int s = tid; s < SS; s += 256) {
        const float v = imp[b * SS + s];
        sum += v;
        if (v > 0.5f) last = s;
    }
#pragma unroll
    for (int m = 1; m < 64; m <<= 1) {
        sum += __shfl_xor(sum, m);
        last = max(last, __shfl_xor(last, m));
    }
    __shared__ float ssum[4]; __shared__ int slast[4];
    if ((tid & 63) == 0) { ssum[tid >> 6] = sum; slast[tid >> 6] = last; }
    __syncthreads();
    if (tid == 0) {
        const float t = ssum[0] + ssum[1] + ssum[2] + ssum[3];
        const int ml = max(max(slast[0], slast[1]), max(slast[2], slast[3]));
        imp_mean[b] = t / (float)SS;
        exists[b] = (ml >= 0) ? 1 : 0;
        s_star[b] = (ml >= 0) ? ml : (SS - 1);
    }
}

// rowmean over H of write_weights; one wave per row
__global__ __launch_bounds__(256) void rowmean_kernel(
    const float* __restrict__ ww, float* __restrict__ rm)
{
    const int wv = threadIdx.x >> 6, lane = threadIdx.x & 63;
    const int row = blockIdx.x * 4 + wv;
    const float* p = ww + (size_t)row * HH + lane * 8;
    const float4 v0 = *(const float4*)p;
    const float4 v1 = *(const float4*)(p + 4);
    float s = v0.x + v0.y + v0.z + v0.w + v1.x + v1.y + v1.z + v1.w;
#pragma unroll
    for (int m = 1; m < 64; m <<= 1) s += __shfl_xor(s, m);
    if (lane == 0) rm[row] = s * (1.0f / (float)HH);
}

// per batch: first-occurrence argmax over M rowmeans
__global__ __launch_bounds__(256) void argmax_kernel(
    const float* __restrict__ rm, int* __restrict__ pos)
{
    const int b = blockIdx.x, tid = threadIdx.x;
    float best = -3.0e38f; int bidx = 1 << 30;
    for (int m = tid; m < MM; m += 256) {
        const float v = rm[b * MM + m];
        if (v > best || (v == best && m < bidx)) { best = v; bidx = m; }
    }
#pragma unroll
    for (int msk = 1; msk < 64; msk <<= 1) {
        const float ov = __shfl_xor(best, msk);
        const int oi = __shfl_xor(bidx, msk);
        if (ov > best || (ov == best && oi < bidx)) { best = ov; bidx = oi; }
    }
    __shared__ float sv[4]; __shared__ int si[4];
    if ((tid & 63) == 0) { sv[tid >> 6] = best; si[tid >> 6] = bidx; }
    __syncthreads();
    if (tid == 0) {
        for (int w = 1; w < 4; ++w)
            if (sv[w] > best || (sv[w] == best && si[w] < bidx)) { best = sv[w]; bidx = si[w]; }
        pos[b] = bidx;
    }
}

// per batch: upd = tanh(relu([old,sel]@Wu1+bu1)@Wu2+bu2); write updated row
__global__ __launch_bounds__(256) void update_kernel(
    const float* __restrict__ mb, const float* __restrict__ ni,
    const float* __restrict__ Wu1, const float* __restrict__ bu1,
    const float* __restrict__ Wu2, const float* __restrict__ bu2,
    const float* __restrict__ wwp, const int* __restrict__ pos,
    const int* __restrict__ s_star, const int* __restrict__ exists,
    float* __restrict__ outu)
{
    const int b = blockIdx.x, tid = threadIdx.x;
    __shared__ float comb[2 * DD];
    __shared__ float hu[HH];
    const int p = pos[b], ss = s_star[b], ex = exists[b];
    const float* oldp = mb + ((size_t)(b * MM + p)) * DD;
    const float* selp = ni + ((size_t)(b * SS + ss)) * DD;
    for (int i = tid; i < DD; i += 256) { comb[i] = oldp[i]; comb[DD + i] = selp[i]; }
    __syncthreads();
#pragma unroll
    for (int t = 0; t < 2; ++t) {
        const int n = tid + t * 256;
        float a = bu1[n];
        for (int k = 0; k < 2 * DD; ++k) a = fmaf(comb[k], Wu1[(size_t)k * HH + n], a);
        hu[n] = fmaxf(a, 0.f);
    }
    __syncthreads();
#pragma unroll
    for (int t = 0; t < 2; ++t) {
        const int n = tid + t * 256;
        float a = bu2[n];
        for (int k = 0; k < HH; ++k) a = fmaf(hu[k], Wu2[(size_t)k * HH + n], a);
        const float upd = tanhf(a);
        const float wwv = wwp[((size_t)(b * MM + p)) * HH + n];
        const float ov = oldp[n];
        outu[((size_t)(b * MM + p)) * DD + n] = ex ? fmaf(upd, wwv, ov) : ov;
    }
}

extern "C" void kernel_launch(void* const* d_in, const int* in_sizes, int n_in,
                              void* d_out, int out_size, void* d_ws, size_t ws_size,
                              hipStream_t stream)
{
    const float* new_info    = (const float*)d_in[0];
    const float* memory_bank = (const float*)d_in[1];
    const float* W_in = (const float*)d_in[2];  const float* b_in = (const float*)d_in[3];
    const float* Wq   = (const float*)d_in[4];  const float* bq   = (const float*)d_in[5];
    const float* Wk   = (const float*)d_in[6];  const float* bk   = (const float*)d_in[7];
    const float* Wv   = (const float*)d_in[8];  const float* bv   = (const float*)d_in[9];
    const float* Wo   = (const float*)d_in[10]; const float* bo   = (const float*)d_in[11];
    const float* Wi1  = (const float*)d_in[12]; const float* bi1  = (const float*)d_in[13];
    const float* Wi2  = (const float*)d_in[14]; const float* bi2  = (const float*)d_in[15];
    const float* Wu1  = (const float*)d_in[16]; const float* bu1  = (const float*)d_in[17];
    const float* Wu2  = (const float*)d_in[18]; const float* bu2  = (const float*)d_in[19];

    float* out = (float*)d_out;
    float* out_updated = out;                               // B*M*D
    float* out_ww      = out + (size_t)BB * MM * HH;        // B*M*H
    float* out_imp     = out + 2 * (size_t)BB * MM * HH;    // B*S

    float* ws = (float*)d_ws;
    float* info_proj = ws;                               // B*S*H
    float* mem_proj  = info_proj + (size_t)BB * SS * HH; // B*M*H
    float* khb       = mem_proj + (size_t)BB * MM * HH;  // B*S*H
    float* vhb       = khb + (size_t)BB * SS * HH;       // B*S*H
    float* qhb       = vhb + (size_t)BB * SS * HH;       // B*M*H
    float* small     = qhb + (size_t)BB * MM * HH;
    float* hidden1   = qhb;                              // reused before qh gemm
    float* rowmean   = small;
    float* imp_mean  = rowmean + (size_t)BB * MM;
    int*   ipos      = (int*)(imp_mean + BB);
    int*   istar     = ipos + BB;
    int*   iexists   = istar + BB;

    const dim3 blk(256);

    hipMemcpyAsync(out_updated, memory_bank,
                   (size_t)BB * MM * DD * sizeof(float),
                   hipMemcpyDeviceToDevice, stream);

    gemm128<<<dim3(4, 64), blk, 0, stream>>>(new_info, W_in, b_in, info_proj,
                                             DD, HH, 0, nullptr, 1);
    gemm128<<<dim3(4, 128), blk, 0, stream>>>(memory_bank, W_in, b_in, mem_proj,
                                              DD, HH, 0, nullptr, 1);
    gemm128<<<dim3(2, 64), blk, 0, stream>>>(info_proj, Wi1, bi1, hidden1,
                                             HH, HH / 2, 1, nullptr, 1);
    imp_kernel<<<dim3((BB * SS) / 4), blk, 0, stream>>>(hidden1, Wi2, bi2, out_imp);
    impstats_kernel<<<dim3(BB), blk, 0, stream>>>(out_imp, imp_mean, istar, iexists);
    gemm128<<<dim3(4, 128), blk, 0, stream>>>(mem_proj, Wq, bq, qhb,
                                              HH, HH, 0, nullptr, 1);
    gemm128<<<dim3(4, 64), blk, 0, stream>>>(info_proj, Wk, bk, khb,
                                             HH, HH, 0, nullptr, 1);
    gemm128<<<dim3(4, 64), blk, 0, stream>>>(info_proj, Wv, bv, vhb,
                                             HH, HH, 0, nullptr, 1);
    attn_kernel<<<dim3(MM / 128, NHEAD, BB), blk, 0, stream>>>(qhb, khb, vhb, qhb);
    gemm128<<<dim3(4, 128), blk, 0, stream>>>(qhb, Wo, bo, out_ww,
                                              HH, HH, 0, imp_mean, MM);
    rowmean_kernel<<<dim3((BB * MM) / 4), blk, 0, stream>>>(out_ww, rowmean);
    argmax_kernel<<<dim3(BB), blk, 0, stream>>>(rowmean, ipos);
    update_kernel<<<dim3(BB), blk, 0, stream>>>(memory_bank, new_info,
                                                Wu1, bu1, Wu2, bu2, out_ww,
                                                ipos, istar, iexists, out_updated);
}